// Round 2
// baseline (372.304 us; speedup 1.0000x reference)
//
#include <hip/hip_runtime.h>
#include <hip/hip_bf16.h>

// Fused MHA block: qkv proj -> flash attention -> out proj.
// All matmuls in bf16 MFMA (16x16x32), fp32 accumulate, fp32 softmax.
// Workspace layout (bytes):
//   [0,8M)   xb   : x cast to bf16           [4096][1024]
//   [8,14M)  wqb  : qkv_w bf16               [3072][1024]
//   [14,16M) pwb  : proj_w bf16              [1024][1024]
//   [16,24M) Qb   : Q*0.125 bf16 per head    [(b*16+h)*2048+n][64]
//   [24,32M) Kb   : K bf16 per head          [(b*16+h)*2048+n][64]
//   [32,40M) Vt   : V bf16 transposed        [(b*16+h)*64+hd][2048]
//   [40,48M) Ob   : attention out bf16       [b*2048+n][1024]

#define DEV __device__ __forceinline__

typedef __attribute__((ext_vector_type(8))) __bf16 bf16x8;
typedef __attribute__((ext_vector_type(4))) float f32x4;

static DEV unsigned short f2bf(float f) {
  unsigned u = __builtin_bit_cast(unsigned, f);
  u += 0x7FFFu + ((u >> 16) & 1u);   // round-to-nearest-even; inputs are finite
  return (unsigned short)(u >> 16);
}

static DEV void gld16(const void* g, void* l) {
  __builtin_amdgcn_global_load_lds(
      (const __attribute__((address_space(1))) unsigned int*)g,
      (__attribute__((address_space(3))) unsigned int*)l, 16, 0, 0);
}

static DEV f32x4 mfma16(bf16x8 a, bf16x8 b, f32x4 c) {
  return __builtin_amdgcn_mfma_f32_16x16x32_bf16(a, b, c, 0, 0, 0);
}

// ---------------- fp32 -> bf16 convert (exact-sized grid, 4 elem/thread) ----
__global__ void k_f2bf(const float* __restrict__ s, unsigned short* __restrict__ d) {
  int i = (blockIdx.x * 256 + threadIdx.x) * 4;
  float4 v = *reinterpret_cast<const float4*>(s + i);
  union { unsigned short h[4]; uint2 u; } cv;
  cv.h[0] = f2bf(v.x); cv.h[1] = f2bf(v.y); cv.h[2] = f2bf(v.z); cv.h[3] = f2bf(v.w);
  *reinterpret_cast<uint2*>(d + i) = cv.u;
}

// ---------------- QKV GEMM: C[4096][3072] = xb @ wqb^T + bias --------------
// 128x128 tile, BK=32, 4 waves (2x2), each wave 64x64 = 4x4 fragments.
__global__ __launch_bounds__(256) void k_qkv(
    const unsigned short* __restrict__ A, const unsigned short* __restrict__ W,
    const float* __restrict__ bias, unsigned short* __restrict__ Qb,
    unsigned short* __restrict__ Kb, unsigned short* __restrict__ Vt) {
  const int K = 1024;
  __shared__ __align__(16) unsigned short As[128 * 32], Bs[128 * 32];
  const int tid = threadIdx.x, lane = tid & 63, wid = tid >> 6;
  const int wm = wid >> 1, wn = wid & 1, fr = lane & 15, fg = lane >> 4;
  const size_t bm = blockIdx.x, bn = blockIdx.y;
  const unsigned short* gA = A + bm * 128 * K;
  const unsigned short* gW = W + bn * 128 * K;
  f32x4 acc[4][4] = {};
  for (int k0 = 0; k0 < K; k0 += 32) {
#pragma unroll
    for (int c = 0; c < 2; ++c) {
      int bi = c * 4096 + wid * 1024 + lane * 16;  // byte index within 8KB tile
      int row = bi >> 6, ce = (bi & 63) >> 1;      // ce = element offset in row
      gld16(gA + (size_t)row * K + k0 + ce, As + c * 2048 + wid * 512);
      gld16(gW + (size_t)row * K + k0 + ce, Bs + c * 2048 + wid * 512);
    }
    __syncthreads();
    bf16x8 af[4], bw[4];
#pragma unroll
    for (int m = 0; m < 4; ++m)
      af[m] = *reinterpret_cast<const bf16x8*>(As + (wm * 64 + m * 16 + fr) * 32 + fg * 8);
#pragma unroll
    for (int n = 0; n < 4; ++n)
      bw[n] = *reinterpret_cast<const bf16x8*>(Bs + (wn * 64 + n * 16 + fr) * 32 + fg * 8);
#pragma unroll
    for (int m = 0; m < 4; ++m)
#pragma unroll
      for (int n = 0; n < 4; ++n)
        acc[m][n] = mfma16(af[m], bw[n], acc[m][n]);
    __syncthreads();
  }
  float bv[4];
#pragma unroll
  for (int n = 0; n < 4; ++n) bv[n] = bias[bn * 128 + wn * 64 + n * 16 + fr];
#pragma unroll
  for (int m = 0; m < 4; ++m)
#pragma unroll
    for (int n = 0; n < 4; ++n)
#pragma unroll
      for (int r = 0; r < 4; ++r) {
        int row = wm * 64 + m * 16 + fg * 4 + r;
        int token = (int)bm * 128 + row;
        int b_ = token >> 11, nn = token & 2047;
        int f = (int)bn * 128 + wn * 64 + n * 16 + fr;
        float val = acc[m][n][r] + bv[n];
        int t = f >> 10, d = f & 1023, h = d >> 6, hd = d & 63;
        size_t bh = (size_t)(b_ * 16 + h);
        if (t == 0)      Qb[(bh * 2048 + nn) * 64 + hd] = f2bf(val * 0.125f);
        else if (t == 1) Kb[(bh * 2048 + nn) * 64 + hd] = f2bf(val);
        else             Vt[(bh * 64 + hd) * 2048 + nn] = f2bf(val);
      }
}

// ---------------- Flash attention (swapped-QK^T, in-register softmax) ------
// grid 1024 = (b,h)=32 x 32 q-tiles of 64; 4 waves x 16 q-rows; KV tile 64.
// Swapped QK^T: S^T = mfma(K_frag, Q_frag) puts P[q=fr][k=nf*16+fg*4+reg]
// in registers -> row softmax = in-lane reduce over 16 + 2 shfl_xor, and
// P staging packs to 4 x ds_write_b64 (vs 32 scalar b16 writes before).
__global__ __launch_bounds__(256) void k_attn(
    const unsigned short* __restrict__ Qb, const unsigned short* __restrict__ Kb,
    const unsigned short* __restrict__ Vt, unsigned short* __restrict__ Ob) {
  __shared__ __align__(16) unsigned short p_lds[4][16][72];  // wave-private P
  const int tid = threadIdx.x, lane = tid & 63, w = tid >> 6;
  const int fr = lane & 15, fg = lane >> 4;
  // bijective XCD swizzle: 1024 blocks % 8 == 0 -> each XCD gets 128
  // consecutive original ids = 4 heads' K/V (2MB, fits 4MB L2).
  const int bid = (int)(blockIdx.x & 7) * 128 + (int)(blockIdx.x >> 3);
  const int qt = bid & 31, bh = bid >> 5;
  const unsigned short* Qp = Qb + ((size_t)bh * 2048 + qt * 64 + w * 16) * 64;
  const unsigned short* Kp = Kb + (size_t)bh * 2048 * 64;
  const unsigned short* Vp = Vt + (size_t)bh * 64 * 2048;
  bf16x8 qf[2];
#pragma unroll
  for (int ks = 0; ks < 2; ++ks)
    qf[ks] = *reinterpret_cast<const bf16x8*>(Qp + fr * 64 + ks * 32 + fg * 8);
  f32x4 accO[4] = {};
  float mrow = -1e30f, lrow = 0.f;

  for (int kt = 0; kt < 32; ++kt) {
    const unsigned short* Kt = Kp + kt * 64 * 64;
    // prefetch V fragments (B-operand: row d, contiguous kv) - hides under QK+softmax
    bf16x8 vf[2][4];
#pragma unroll
    for (int ks = 0; ks < 2; ++ks)
#pragma unroll
      for (int df = 0; df < 4; ++df)
        vf[ks][df] = *reinterpret_cast<const bf16x8*>(
            Vp + (size_t)(df * 16 + fr) * 2048 + kt * 64 + ks * 32 + fg * 8);
    // S^T tile: rows k (4 frags of 16), cols q (16)
    f32x4 s[4] = {};
#pragma unroll
    for (int nf = 0; nf < 4; ++nf)
#pragma unroll
      for (int ks = 0; ks < 2; ++ks) {
        bf16x8 kf = *reinterpret_cast<const bf16x8*>(Kt + (nf * 16 + fr) * 64 + ks * 32 + fg * 8);
        s[nf] = mfma16(kf, qf[ks], s[nf]);
      }
    // in-register row softmax: lane owns q=fr, k = nf*16 + fg*4 + reg
    float m01 = fmaxf(fmaxf(fmaxf(s[0][0], s[0][1]), fmaxf(s[0][2], s[0][3])),
                      fmaxf(fmaxf(s[1][0], s[1][1]), fmaxf(s[1][2], s[1][3])));
    float m23 = fmaxf(fmaxf(fmaxf(s[2][0], s[2][1]), fmaxf(s[2][2], s[2][3])),
                      fmaxf(fmaxf(s[3][0], s[3][1]), fmaxf(s[3][2], s[3][3])));
    float pmax = fmaxf(m01, m23);
    pmax = fmaxf(pmax, __shfl_xor(pmax, 16));
    pmax = fmaxf(pmax, __shfl_xor(pmax, 32));
    float mnew = fmaxf(mrow, pmax);
    float sc = __expf(mrow - mnew);
    mrow = mnew;
    float rs = 0.f;
#pragma unroll
    for (int nf = 0; nf < 4; ++nf)
#pragma unroll
      for (int r = 0; r < 4; ++r) {
        float p = __expf(s[nf][r] - mnew);
        s[nf][r] = p;
        rs += p;
      }
    rs += __shfl_xor(rs, 16);
    rs += __shfl_xor(rs, 32);
    lrow = lrow * sc + rs;
    // broadcast rescale factor to accO layout (accO q = fg*4+reg)
    float scq[4];
#pragma unroll
    for (int r = 0; r < 4; ++r) scq[r] = __shfl(sc, fg * 4 + r);
#pragma unroll
    for (int df = 0; df < 4; ++df)
#pragma unroll
      for (int r = 0; r < 4; ++r) accO[df][r] *= scq[r];
    // P -> LDS: 4 consecutive k per (nf) pack into one b64 write
#pragma unroll
    for (int nf = 0; nf < 4; ++nf) {
      union { unsigned short h[4]; uint2 u; } pk;
#pragma unroll
      for (int r = 0; r < 4; ++r) pk.h[r] = f2bf(s[nf][r]);
      *reinterpret_cast<uint2*>(&p_lds[w][fr][nf * 16 + fg * 4]) = pk.u;
    }
    // read back as PV A-fragments (row q=fr, contiguous k)
    bf16x8 pf[2];
#pragma unroll
    for (int ks = 0; ks < 2; ++ks)
      pf[ks] = *reinterpret_cast<const bf16x8*>(&p_lds[w][fr][ks * 32 + fg * 8]);
#pragma unroll
    for (int df = 0; df < 4; ++df)
#pragma unroll
      for (int ks = 0; ks < 2; ++ks)
        accO[df] = mfma16(pf[ks], vf[ks][df], accO[df]);
  }
  // epilogue: O[q][d], q = fg*4+reg, d = df*16+fr; l lives at lane q=fr
  float linv = 1.f / lrow;
  float lq[4];
#pragma unroll
  for (int r = 0; r < 4; ++r) lq[r] = __shfl(linv, fg * 4 + r);
  const int b_ = bh >> 4, h = bh & 15;
#pragma unroll
  for (int df = 0; df < 4; ++df)
#pragma unroll
    for (int r = 0; r < 4; ++r) {
      int nn = qt * 64 + w * 16 + fg * 4 + r;
      int d = df * 16 + fr;
      Ob[(size_t)(b_ * 2048 + nn) * 1024 + h * 64 + d] = f2bf(accO[df][r] * lq[r]);
    }
}

// ---------------- Proj GEMM: out[4096][1024] = Ob @ pwb^T + bias (fp32 out) -
__global__ __launch_bounds__(256) void k_proj(
    const unsigned short* __restrict__ A, const unsigned short* __restrict__ W,
    const float* __restrict__ bias, float* __restrict__ out) {
  const int K = 1024;
  __shared__ __align__(16) unsigned short As[128 * 32], Bs[128 * 32];
  const int tid = threadIdx.x, lane = tid & 63, wid = tid >> 6;
  const int wm = wid >> 1, wn = wid & 1, fr = lane & 15, fg = lane >> 4;
  const size_t bm = blockIdx.x, bn = blockIdx.y;
  const unsigned short* gA = A + bm * 128 * K;
  const unsigned short* gW = W + bn * 128 * K;
  f32x4 acc[4][4] = {};
  for (int k0 = 0; k0 < K; k0 += 32) {
#pragma unroll
    for (int c = 0; c < 2; ++c) {
      int bi = c * 4096 + wid * 1024 + lane * 16;
      int row = bi >> 6, ce = (bi & 63) >> 1;
      gld16(gA + (size_t)row * K + k0 + ce, As + c * 2048 + wid * 512);
      gld16(gW + (size_t)row * K + k0 + ce, Bs + c * 2048 + wid * 512);
    }
    __syncthreads();
    bf16x8 af[4], bw[4];
#pragma unroll
    for (int m = 0; m < 4; ++m)
      af[m] = *reinterpret_cast<const bf16x8*>(As + (wm * 64 + m * 16 + fr) * 32 + fg * 8);
#pragma unroll
    for (int n = 0; n < 4; ++n)
      bw[n] = *reinterpret_cast<const bf16x8*>(Bs + (wn * 64 + n * 16 + fr) * 32 + fg * 8);
#pragma unroll
    for (int m = 0; m < 4; ++m)
#pragma unroll
      for (int n = 0; n < 4; ++n)
        acc[m][n] = mfma16(af[m], bw[n], acc[m][n]);
    __syncthreads();
  }
  float bv[4];
#pragma unroll
  for (int n = 0; n < 4; ++n) bv[n] = bias[bn * 128 + wn * 64 + n * 16 + fr];
#pragma unroll
  for (int m = 0; m < 4; ++m)
#pragma unroll
    for (int n = 0; n < 4; ++n)
#pragma unroll
      for (int r = 0; r < 4; ++r) {
        size_t token = bm * 128 + wm * 64 + m * 16 + fg * 4 + r;
        int f = (int)bn * 128 + wn * 64 + n * 16 + fr;
        out[token * 1024 + f] = acc[m][n][r] + bv[n];
      }
}

extern "C" void kernel_launch(void* const* d_in, const int* in_sizes, int n_in,
                              void* d_out, int out_size, void* d_ws, size_t ws_size,
                              hipStream_t stream) {
  const float* x      = (const float*)d_in[0];
  const float* qkv_w  = (const float*)d_in[1];
  const float* qkv_b  = (const float*)d_in[2];
  const float* proj_w = (const float*)d_in[3];
  const float* proj_b = (const float*)d_in[4];
  float* out = (float*)d_out;
  char* ws = (char*)d_ws;
  unsigned short* xb  = (unsigned short*)(ws);
  unsigned short* wqb = (unsigned short*)(ws + (size_t)(8u << 20));
  unsigned short* pwb = (unsigned short*)(ws + (size_t)(14u << 20));
  unsigned short* Qb  = (unsigned short*)(ws + (size_t)(16u << 20));
  unsigned short* Kb  = (unsigned short*)(ws + (size_t)(24u << 20));
  unsigned short* Vt  = (unsigned short*)(ws + (size_t)(32u << 20));
  unsigned short* Ob  = (unsigned short*)(ws + (size_t)(40u << 20));

  k_f2bf<<<4096, 256, 0, stream>>>(x, xb);        // 4096*1024   elems
  k_f2bf<<<3072, 256, 0, stream>>>(qkv_w, wqb);   // 3072*1024
  k_f2bf<<<1024, 256, 0, stream>>>(proj_w, pwb);  // 1024*1024
  k_qkv<<<dim3(32, 24), 256, 0, stream>>>(xb, wqb, qkv_b, Qb, Kb, Vt);
  k_attn<<<1024, 256, 0, stream>>>(Qb, Kb, Vt, Ob);
  k_proj<<<dim3(32, 8), 256, 0, stream>>>(Ob, pwb, proj_b, out);
}

// Round 3
// 224.041 us; speedup vs baseline: 1.6618x; 1.6618x over previous
//
#include <hip/hip_runtime.h>
#include <hip/hip_bf16.h>

// Fused MHA block: qkv proj -> flash attention -> out proj.
// All matmuls in bf16 MFMA (16x16x32), fp32 accumulate, fp32 softmax.
// Workspace layout (bytes):
//   [0,8M)   xb   : x cast to bf16           [4096][1024]
//   [8,14M)  wqb  : qkv_w bf16               [3072][1024]
//   [14,16M) pwb  : proj_w bf16              [1024][1024]
//   [16,24M) Qb   : Q*0.125 bf16 per head    [(b*16+h)*2048+n][64]
//   [24,32M) Kb   : K bf16 per head          [(b*16+h)*2048+n][64]
//   [32,40M) Vt   : V bf16 transposed        [(b*16+h)*64+hd][2048]
//   [40,48M) Ob   : attention out bf16       [b*2048+n][1024]

#define DEV __device__ __forceinline__

typedef __attribute__((ext_vector_type(8))) __bf16 bf16x8;
typedef __attribute__((ext_vector_type(4))) float f32x4;

static DEV unsigned short f2bf(float f) {
  unsigned u = __builtin_bit_cast(unsigned, f);
  u += 0x7FFFu + ((u >> 16) & 1u);   // round-to-nearest-even; inputs are finite
  return (unsigned short)(u >> 16);
}

static DEV void gld16(const void* g, void* l) {
  __builtin_amdgcn_global_load_lds(
      (const __attribute__((address_space(1))) unsigned int*)g,
      (__attribute__((address_space(3))) unsigned int*)l, 16, 0, 0);
}

static DEV f32x4 mfma16(bf16x8 a, bf16x8 b, f32x4 c) {
  return __builtin_amdgcn_mfma_f32_16x16x32_bf16(a, b, c, 0, 0, 0);
}

// ---------------- fp32 -> bf16 convert (exact-sized grid, 4 elem/thread) ----
__global__ void k_f2bf(const float* __restrict__ s, unsigned short* __restrict__ d) {
  int i = (blockIdx.x * 256 + threadIdx.x) * 4;
  float4 v = *reinterpret_cast<const float4*>(s + i);
  union { unsigned short h[4]; uint2 u; } cv;
  cv.h[0] = f2bf(v.x); cv.h[1] = f2bf(v.y); cv.h[2] = f2bf(v.z); cv.h[3] = f2bf(v.w);
  *reinterpret_cast<uint2*>(d + i) = cv.u;
}

// ---------------- QKV GEMM: C[4096][3072] = xb @ wqb^T + bias --------------
// 128x128 tile, BK=32, 4 waves (2x2), each wave 64x64 = 4x4 fragments.
__global__ __launch_bounds__(256) void k_qkv(
    const unsigned short* __restrict__ A, const unsigned short* __restrict__ W,
    const float* __restrict__ bias, unsigned short* __restrict__ Qb,
    unsigned short* __restrict__ Kb, unsigned short* __restrict__ Vt) {
  const int K = 1024;
  __shared__ __align__(16) unsigned short As[128 * 32], Bs[128 * 32];
  const int tid = threadIdx.x, lane = tid & 63, wid = tid >> 6;
  const int wm = wid >> 1, wn = wid & 1, fr = lane & 15, fg = lane >> 4;
  const size_t bm = blockIdx.x, bn = blockIdx.y;
  const unsigned short* gA = A + bm * 128 * K;
  const unsigned short* gW = W + bn * 128 * K;
  f32x4 acc[4][4] = {};
  for (int k0 = 0; k0 < K; k0 += 32) {
#pragma unroll
    for (int c = 0; c < 2; ++c) {
      int bi = c * 4096 + wid * 1024 + lane * 16;  // byte index within 8KB tile
      int row = bi >> 6, ce = (bi & 63) >> 1;      // ce = element offset in row
      gld16(gA + (size_t)row * K + k0 + ce, As + c * 2048 + wid * 512);
      gld16(gW + (size_t)row * K + k0 + ce, Bs + c * 2048 + wid * 512);
    }
    __syncthreads();
    bf16x8 af[4], bw[4];
#pragma unroll
    for (int m = 0; m < 4; ++m)
      af[m] = *reinterpret_cast<const bf16x8*>(As + (wm * 64 + m * 16 + fr) * 32 + fg * 8);
#pragma unroll
    for (int n = 0; n < 4; ++n)
      bw[n] = *reinterpret_cast<const bf16x8*>(Bs + (wn * 64 + n * 16 + fr) * 32 + fg * 8);
#pragma unroll
    for (int m = 0; m < 4; ++m)
#pragma unroll
      for (int n = 0; n < 4; ++n)
        acc[m][n] = mfma16(af[m], bw[n], acc[m][n]);
    __syncthreads();
  }
  float bv[4];
#pragma unroll
  for (int n = 0; n < 4; ++n) bv[n] = bias[bn * 128 + wn * 64 + n * 16 + fr];
#pragma unroll
  for (int m = 0; m < 4; ++m)
#pragma unroll
    for (int n = 0; n < 4; ++n)
#pragma unroll
      for (int r = 0; r < 4; ++r) {
        int row = wm * 64 + m * 16 + fg * 4 + r;
        int token = (int)bm * 128 + row;
        int b_ = token >> 11, nn = token & 2047;
        int f = (int)bn * 128 + wn * 64 + n * 16 + fr;
        float val = acc[m][n][r] + bv[n];
        int t = f >> 10, d = f & 1023, h = d >> 6, hd = d & 63;
        size_t bh = (size_t)(b_ * 16 + h);
        if (t == 0)      Qb[(bh * 2048 + nn) * 64 + hd] = f2bf(val * 0.125f);
        else if (t == 1) Kb[(bh * 2048 + nn) * 64 + hd] = f2bf(val);
        else             Vt[(bh * 64 + hd) * 2048 + nn] = f2bf(val);
      }
}

// ---------------- Flash attention -----------------------------------------
// grid 1024 = (b,h)=32 x 32 q-tiles of 64; 4 waves x 16 q-rows; KV tile 64.
// Swapped QK^T (S^T = mfma(K,Q)) -> P[q=fr][k in-register] -> softmax with
// defer-max (T13): steady state has ZERO cross-lane ops. K/V staged to LDS
// once per block via global_load_lds, double-buffered (T3 2-phase), with
// XOR-swizzle (T2, rule #21: linear LDS dest + inverse-swizzled global src
// + swizzled reads).
__global__ __launch_bounds__(256) void k_attn(
    const unsigned short* __restrict__ Qb, const unsigned short* __restrict__ Kb,
    const unsigned short* __restrict__ Vt, unsigned short* __restrict__ Ob) {
  __shared__ __align__(16) unsigned short Ks[2][64 * 64];
  __shared__ __align__(16) unsigned short Vs[2][64 * 64];
  __shared__ __align__(16) unsigned short p_lds[4][16 * 64];  // wave-private
  const int tid = threadIdx.x, lane = tid & 63, w = tid >> 6;
  const int fr = lane & 15, fg = lane >> 4;
  // bijective XCD swizzle: 1024 blocks % 8 == 0 -> each XCD gets 128
  // consecutive original ids = 4 heads' K/V (2MB, fits 4MB L2).
  const int bid = (int)(blockIdx.x & 7) * 128 + (int)(blockIdx.x >> 3);
  const int qt = bid & 31, bh = bid >> 5;
  const unsigned short* Qp = Qb + ((size_t)bh * 2048 + qt * 64 + w * 16) * 64;
  const unsigned short* Kp = Kb + (size_t)bh * 2048 * 64;
  const unsigned short* Vp = Vt + (size_t)bh * 64 * 2048;

  // staging geometry: per wave, 2 chunks of 1KB each for K and V.
  // LDS chunk (row, slot) holds global chunk (row, slot ^ (row&7)).
  const int crow0 = w * 16 + (lane >> 3);        // j=0 row; j=1 adds 8
  bf16x8 qf[2];
#pragma unroll
  for (int ks = 0; ks < 2; ++ks)
    qf[ks] = *reinterpret_cast<const bf16x8*>(Qp + fr * 64 + ks * 32 + fg * 8);

  f32x4 accO[4] = {};
  float mrow = -1e30f, lpart = 0.f;

#define STAGE(bufi, kti)                                                      \
  {                                                                           \
    const unsigned short* Kt_ = Kp + (kti) * 64 * 64;                         \
    _Pragma("unroll")                                                         \
    for (int j = 0; j < 2; ++j) {                                             \
      int cr = crow0 + j * 8;                                                 \
      int cs = (lane & 7) ^ (cr & 7);                                         \
      gld16(Kt_ + cr * 64 + cs * 8, &Ks[bufi][(w * 2 + j) * 512]);            \
      gld16(Vp + (size_t)cr * 2048 + (kti) * 64 + cs * 8,                     \
            &Vs[bufi][(w * 2 + j) * 512]);                                    \
    }                                                                         \
  }

  STAGE(0, 0);
  __syncthreads();
  int buf = 0;
  for (int kt = 0; kt < 32; ++kt) {
    if (kt < 31) STAGE(buf ^ 1, kt + 1);
    // ---- QK^T from swizzled LDS: row k = nf*16+fr, chunk c = ks*4+fg ----
    f32x4 s[4] = {};
#pragma unroll
    for (int nf = 0; nf < 4; ++nf)
#pragma unroll
      for (int ks = 0; ks < 2; ++ks) {
        bf16x8 kf = *reinterpret_cast<const bf16x8*>(
            &Ks[buf][(nf * 16 + fr) * 64 + (((ks * 4 + fg) ^ (fr & 7)) * 8)]);
        s[nf] = mfma16(kf, qf[ks], s[nf]);
      }
    // ---- V fragments (issue early; lgkm latency hides under softmax) ----
    bf16x8 vf[2][4];
#pragma unroll
    for (int ks = 0; ks < 2; ++ks)
#pragma unroll
      for (int df = 0; df < 4; ++df)
        vf[ks][df] = *reinterpret_cast<const bf16x8*>(
            &Vs[buf][(df * 16 + fr) * 64 + (((ks * 4 + fg) ^ (fr & 7)) * 8)]);
    // ---- softmax, defer-max: steady state = no cross-lane ops ----
    float mymax = fmaxf(
        fmaxf(fmaxf(fmaxf(s[0][0], s[0][1]), fmaxf(s[0][2], s[0][3])),
              fmaxf(fmaxf(s[1][0], s[1][1]), fmaxf(s[1][2], s[1][3]))),
        fmaxf(fmaxf(fmaxf(s[2][0], s[2][1]), fmaxf(s[2][2], s[2][3])),
              fmaxf(fmaxf(s[3][0], s[3][1]), fmaxf(s[3][2], s[3][3]))));
    if (!__all(mymax <= mrow + 8.0f)) {
      float pmax = mymax;
      pmax = fmaxf(pmax, __shfl_xor(pmax, 16));
      pmax = fmaxf(pmax, __shfl_xor(pmax, 32));
      float mnew = fmaxf(mrow, pmax);
      float sc = __expf(mrow - mnew);
      mrow = mnew;
      lpart *= sc;
      float scq[4];
#pragma unroll
      for (int r = 0; r < 4; ++r) scq[r] = __shfl(sc, fg * 4 + r);
#pragma unroll
      for (int df = 0; df < 4; ++df)
#pragma unroll
        for (int r = 0; r < 4; ++r) accO[df][r] *= scq[r];
    }
    float rs = 0.f;
#pragma unroll
    for (int nf = 0; nf < 4; ++nf)
#pragma unroll
      for (int r = 0; r < 4; ++r) {
        float p = __expf(s[nf][r] - mrow);
        s[nf][r] = p;
        rs += p;
      }
    lpart += rs;
    // ---- P -> wave-private LDS (swizzled), read back as A-frags ----
#pragma unroll
    for (int nf = 0; nf < 4; ++nf) {
      union { unsigned short h[4]; uint2 u; } pk;
#pragma unroll
      for (int r = 0; r < 4; ++r) pk.h[r] = f2bf(s[nf][r]);
      *reinterpret_cast<uint2*>(
          &p_lds[w][fr * 64 + (((2 * nf + (fg >> 1)) ^ (fr & 7)) * 8) +
                   (fg & 1) * 4]) = pk.u;
    }
    bf16x8 pf[2];
#pragma unroll
    for (int ks = 0; ks < 2; ++ks)
      pf[ks] = *reinterpret_cast<const bf16x8*>(
          &p_lds[w][fr * 64 + (((ks * 4 + fg) ^ (fr & 7)) * 8)]);
#pragma unroll
    for (int df = 0; df < 4; ++df)
#pragma unroll
      for (int ks = 0; ks < 2; ++ks)
        accO[df] = mfma16(pf[ks], vf[ks][df], accO[df]);
    __syncthreads();
    buf ^= 1;
  }
#undef STAGE
  // epilogue: O[q][d], q = fg*4+reg, d = df*16+fr; l lives at lane q=fr
  float lrow = lpart;
  lrow += __shfl_xor(lrow, 16);
  lrow += __shfl_xor(lrow, 32);
  float linv = 1.f / lrow;
  float lq[4];
#pragma unroll
  for (int r = 0; r < 4; ++r) lq[r] = __shfl(linv, fg * 4 + r);
  const int b_ = bh >> 4, h = bh & 15;
#pragma unroll
  for (int df = 0; df < 4; ++df)
#pragma unroll
    for (int r = 0; r < 4; ++r) {
      int nn = qt * 64 + w * 16 + fg * 4 + r;
      int d = df * 16 + fr;
      Ob[(size_t)(b_ * 2048 + nn) * 1024 + h * 64 + d] = f2bf(accO[df][r] * lq[r]);
    }
}

// ---------------- Proj GEMM: out[4096][1024] = Ob @ pwb^T + bias (fp32 out) -
__global__ __launch_bounds__(256) void k_proj(
    const unsigned short* __restrict__ A, const unsigned short* __restrict__ W,
    const float* __restrict__ bias, float* __restrict__ out) {
  const int K = 1024;
  __shared__ __align__(16) unsigned short As[128 * 32], Bs[128 * 32];
  const int tid = threadIdx.x, lane = tid & 63, wid = tid >> 6;
  const int wm = wid >> 1, wn = wid & 1, fr = lane & 15, fg = lane >> 4;
  const size_t bm = blockIdx.x, bn = blockIdx.y;
  const unsigned short* gA = A + bm * 128 * K;
  const unsigned short* gW = W + bn * 128 * K;
  f32x4 acc[4][4] = {};
  for (int k0 = 0; k0 < K; k0 += 32) {
#pragma unroll
    for (int c = 0; c < 2; ++c) {
      int bi = c * 4096 + wid * 1024 + lane * 16;
      int row = bi >> 6, ce = (bi & 63) >> 1;
      gld16(gA + (size_t)row * K + k0 + ce, As + c * 2048 + wid * 512);
      gld16(gW + (size_t)row * K + k0 + ce, Bs + c * 2048 + wid * 512);
    }
    __syncthreads();
    bf16x8 af[4], bw[4];
#pragma unroll
    for (int m = 0; m < 4; ++m)
      af[m] = *reinterpret_cast<const bf16x8*>(As + (wm * 64 + m * 16 + fr) * 32 + fg * 8);
#pragma unroll
    for (int n = 0; n < 4; ++n)
      bw[n] = *reinterpret_cast<const bf16x8*>(Bs + (wn * 64 + n * 16 + fr) * 32 + fg * 8);
#pragma unroll
    for (int m = 0; m < 4; ++m)
#pragma unroll
      for (int n = 0; n < 4; ++n)
        acc[m][n] = mfma16(af[m], bw[n], acc[m][n]);
    __syncthreads();
  }
  float bv[4];
#pragma unroll
  for (int n = 0; n < 4; ++n) bv[n] = bias[bn * 128 + wn * 64 + n * 16 + fr];
#pragma unroll
  for (int m = 0; m < 4; ++m)
#pragma unroll
    for (int n = 0; n < 4; ++n)
#pragma unroll
      for (int r = 0; r < 4; ++r) {
        size_t token = bm * 128 + wm * 64 + m * 16 + fg * 4 + r;
        int f = (int)bn * 128 + wn * 64 + n * 16 + fr;
        out[token * 1024 + f] = acc[m][n][r] + bv[n];
      }
}

extern "C" void kernel_launch(void* const* d_in, const int* in_sizes, int n_in,
                              void* d_out, int out_size, void* d_ws, size_t ws_size,
                              hipStream_t stream) {
  const float* x      = (const float*)d_in[0];
  const float* qkv_w  = (const float*)d_in[1];
  const float* qkv_b  = (const float*)d_in[2];
  const float* proj_w = (const float*)d_in[3];
  const float* proj_b = (const float*)d_in[4];
  float* out = (float*)d_out;
  char* ws = (char*)d_ws;
  unsigned short* xb  = (unsigned short*)(ws);
  unsigned short* wqb = (unsigned short*)(ws + (size_t)(8u << 20));
  unsigned short* pwb = (unsigned short*)(ws + (size_t)(14u << 20));
  unsigned short* Qb  = (unsigned short*)(ws + (size_t)(16u << 20));
  unsigned short* Kb  = (unsigned short*)(ws + (size_t)(24u << 20));
  unsigned short* Vt  = (unsigned short*)(ws + (size_t)(32u << 20));
  unsigned short* Ob  = (unsigned short*)(ws + (size_t)(40u << 20));

  k_f2bf<<<4096, 256, 0, stream>>>(x, xb);        // 4096*1024   elems
  k_f2bf<<<3072, 256, 0, stream>>>(qkv_w, wqb);   // 3072*1024
  k_f2bf<<<1024, 256, 0, stream>>>(proj_w, pwb);  // 1024*1024
  k_qkv<<<dim3(32, 24), 256, 0, stream>>>(xb, wqb, qkv_b, Qb, Kb, Vt);
  k_attn<<<1024, 256, 0, stream>>>(Qb, Kb, Vt, Ob);
  k_proj<<<dim3(32, 8), 256, 0, stream>>>(Ob, pwb, proj_b, out);
}

// Round 5
// 206.226 us; speedup vs baseline: 1.8053x; 1.0864x over previous
//
#include <hip/hip_runtime.h>
#include <hip/hip_bf16.h>

// Fused MHA block: qkv proj -> flash attention -> out proj.
// All matmuls in bf16 MFMA (16x16x32), fp32 accumulate, exp2-domain softmax.
// Workspace layout (bytes):
//   [0,8M)   xb   : x cast to bf16           [4096][1024]
//   [8,14M)  wqb  : qkv_w bf16               [3072][1024]
//   [14,16M) pwb  : proj_w bf16              [1024][1024]
//   [16,24M) Qb   : Q*0.125*log2e bf16       [(b*16+h)*2048+n][64]
//   [24,32M) Kb   : K bf16 per head          [(b*16+h)*2048+n][64]
//   [32,40M) Vt   : V bf16 transposed        [(b*16+h)*64+hd][2048]
//   [40,48M) Ob   : attention out bf16       [b*2048+n][1024]

#define DEV __device__ __forceinline__

typedef __attribute__((ext_vector_type(8))) __bf16 bf16x8;
typedef __attribute__((ext_vector_type(4))) float f32x4;

// RNE f32->bf16 (bit-twiddle; proven rounds 1-3). NOTE: do NOT replace with
// inline-asm v_cvt_pk_bf16_f32 — round 4 did and absmax went 4.9e-4 -> 6.8e-3.
static DEV unsigned short f2bf(float f) {
  unsigned u = __builtin_bit_cast(unsigned, f);
  u += 0x7FFFu + ((u >> 16) & 1u);
  return (unsigned short)(u >> 16);
}

static DEV float fexp2(float x) {
#if __has_builtin(__builtin_amdgcn_exp2f)
  return __builtin_amdgcn_exp2f(x);   // v_exp_f32 is 2^x
#else
  return __expf(x * 0.69314718055994531f);
#endif
}

static DEV float max3(float a, float b, float c) {
  return fmaxf(fmaxf(a, b), c);       // clang fuses to v_max3_f32
}

static DEV void gld16(const void* g, void* l) {
  __builtin_amdgcn_global_load_lds(
      (const __attribute__((address_space(1))) unsigned int*)g,
      (__attribute__((address_space(3))) unsigned int*)l, 16, 0, 0);
}

static DEV f32x4 mfma16(bf16x8 a, bf16x8 b, f32x4 c) {
  return __builtin_amdgcn_mfma_f32_16x16x32_bf16(a, b, c, 0, 0, 0);
}

// ---------------- fused fp32 -> bf16 convert (x | qkv_w | proj_w) ----------
__global__ void k_conv(const float* __restrict__ x, const float* __restrict__ qw,
                       const float* __restrict__ pw, unsigned short* __restrict__ xb,
                       unsigned short* __restrict__ wqb, unsigned short* __restrict__ pwb) {
  int b = blockIdx.x;
  const float* s;
  unsigned short* d;
  int base;
  if (b < 4096)      { s = x;  d = xb;  base = b; }
  else if (b < 7168) { s = qw; d = wqb; base = b - 4096; }
  else               { s = pw; d = pwb; base = b - 7168; }
  int i = (base * 256 + threadIdx.x) * 4;
  float4 v = *reinterpret_cast<const float4*>(s + i);
  union { unsigned short h[4]; uint2 u; } cv;
  cv.h[0] = f2bf(v.x); cv.h[1] = f2bf(v.y); cv.h[2] = f2bf(v.z); cv.h[3] = f2bf(v.w);
  *reinterpret_cast<uint2*>(d + i) = cv.u;
}

// ---------------- QKV GEMM: C[4096][3072] = xb @ wqb^T + bias --------------
// 128x128 tile, BK=32, 4 waves (2x2), each wave 64x64 = 4x4 fragments.
__global__ __launch_bounds__(256) void k_qkv(
    const unsigned short* __restrict__ A, const unsigned short* __restrict__ W,
    const float* __restrict__ bias, unsigned short* __restrict__ Qb,
    unsigned short* __restrict__ Kb, unsigned short* __restrict__ Vt) {
  const int K = 1024;
  __shared__ __align__(16) unsigned short As[128 * 32], Bs[128 * 32];
  const int tid = threadIdx.x, lane = tid & 63, wid = tid >> 6;
  const int wm = wid >> 1, wn = wid & 1, fr = lane & 15, fg = lane >> 4;
  const size_t bm = blockIdx.x, bn = blockIdx.y;
  const unsigned short* gA = A + bm * 128 * K;
  const unsigned short* gW = W + bn * 128 * K;
  f32x4 acc[4][4] = {};
  for (int k0 = 0; k0 < K; k0 += 32) {
#pragma unroll
    for (int c = 0; c < 2; ++c) {
      int bi = c * 4096 + wid * 1024 + lane * 16;  // byte index within 8KB tile
      int row = bi >> 6, ce = (bi & 63) >> 1;
      gld16(gA + (size_t)row * K + k0 + ce, As + c * 2048 + wid * 512);
      gld16(gW + (size_t)row * K + k0 + ce, Bs + c * 2048 + wid * 512);
    }
    __syncthreads();
    bf16x8 af[4], bw[4];
#pragma unroll
    for (int m = 0; m < 4; ++m)
      af[m] = *reinterpret_cast<const bf16x8*>(As + (wm * 64 + m * 16 + fr) * 32 + fg * 8);
#pragma unroll
    for (int n = 0; n < 4; ++n)
      bw[n] = *reinterpret_cast<const bf16x8*>(Bs + (wn * 64 + n * 16 + fr) * 32 + fg * 8);
#pragma unroll
    for (int m = 0; m < 4; ++m)
#pragma unroll
      for (int n = 0; n < 4; ++n)
        acc[m][n] = mfma16(af[m], bw[n], acc[m][n]);
    __syncthreads();
  }
  const float QSCALE = 0.18033688011112043f;  // 0.125 * log2(e)
  float bv[4];
#pragma unroll
  for (int n = 0; n < 4; ++n) bv[n] = bias[bn * 128 + wn * 64 + n * 16 + fr];
#pragma unroll
  for (int m = 0; m < 4; ++m)
#pragma unroll
    for (int n = 0; n < 4; ++n) {
      int f = (int)bn * 128 + wn * 64 + n * 16 + fr;
      int t = f >> 10, d = f & 1023, h = d >> 6, hd = d & 63;
      int token0 = (int)bm * 128 + wm * 64 + m * 16 + fg * 4;  // r adds 0..3
      int b_ = token0 >> 11, nn0 = token0 & 2047;
      size_t bh = (size_t)(b_ * 16 + h);
      float v0 = acc[m][n][0] + bv[n], v1 = acc[m][n][1] + bv[n];
      float v2 = acc[m][n][2] + bv[n], v3 = acc[m][n][3] + bv[n];
      if (t == 0) {
        unsigned short* q = Qb + (bh * 2048 + nn0) * 64 + hd;
        q[0] = f2bf(v0 * QSCALE); q[64] = f2bf(v1 * QSCALE);
        q[128] = f2bf(v2 * QSCALE); q[192] = f2bf(v3 * QSCALE);
      } else if (t == 1) {
        unsigned short* k = Kb + (bh * 2048 + nn0) * 64 + hd;
        k[0] = f2bf(v0); k[64] = f2bf(v1); k[128] = f2bf(v2); k[192] = f2bf(v3);
      } else {
        union { unsigned short h[4]; uint2 u; } pk;
        pk.h[0] = f2bf(v0); pk.h[1] = f2bf(v1);
        pk.h[2] = f2bf(v2); pk.h[3] = f2bf(v3);
        *reinterpret_cast<uint2*>(Vt + (bh * 64 + hd) * 2048 + nn0) = pk.u;
      }
    }
}

// ---------------- Flash attention -----------------------------------------
// grid 1024 = (b,h)=32 x 32 q-tiles of 64; 4 waves x 16 q-rows; KV tile 64.
// Swapped QK^T (S^T = mfma(K,Q)); exp2-domain softmax with defer-max (T13);
// K/V staged via global_load_lds, static 2-tile double buffer (T3 2-phase),
// XOR-swizzle (T2, rule #21).
static DEV void attn_tile(const unsigned short* __restrict__ Ksb,
                          const unsigned short* __restrict__ Vsb,
                          unsigned short* __restrict__ pw, const bf16x8* qf,
                          int fr, int fg, f32x4* accO, float& mrow, float& lpart) {
  f32x4 s[4] = {};
#pragma unroll
  for (int nf = 0; nf < 4; ++nf)
#pragma unroll
    for (int ks = 0; ks < 2; ++ks) {
      bf16x8 kf = *reinterpret_cast<const bf16x8*>(
          &Ksb[(nf * 16 + fr) * 64 + (((ks * 4 + fg) ^ (fr & 7)) * 8)]);
      s[nf] = mfma16(kf, qf[ks], s[nf]);
    }
  bf16x8 vf[2][4];
#pragma unroll
  for (int ks = 0; ks < 2; ++ks)
#pragma unroll
    for (int df = 0; df < 4; ++df)
      vf[ks][df] = *reinterpret_cast<const bf16x8*>(
          &Vsb[(df * 16 + fr) * 64 + (((ks * 4 + fg) ^ (fr & 7)) * 8)]);
  // row max over this lane's 16 scores (v_max3 tree)
  float m0 = max3(s[0][0], s[0][1], s[0][2]);
  float m1 = max3(s[0][3], s[1][0], s[1][1]);
  float m2 = max3(s[1][2], s[1][3], s[2][0]);
  float m3 = max3(s[2][1], s[2][2], s[2][3]);
  float m4 = max3(s[3][0], s[3][1], s[3][2]);
  float mymax = fmaxf(max3(m0, m1, m2), max3(m3, m4, s[3][3]));
  if (!__all(mymax <= mrow + 8.0f)) {   // defer-max: rare path
    float pmax = fmaxf(mymax, __shfl_xor(mymax, 16));
    pmax = fmaxf(pmax, __shfl_xor(pmax, 32));
    float mnew = fmaxf(mrow, pmax);
    float sc = fexp2(mrow - mnew);
    mrow = mnew;
    lpart *= sc;
    float scq[4];
#pragma unroll
    for (int r = 0; r < 4; ++r) scq[r] = __shfl(sc, fg * 4 + r);
#pragma unroll
    for (int df = 0; df < 4; ++df)
#pragma unroll
      for (int r = 0; r < 4; ++r) accO[df][r] *= scq[r];
  }
  float rs = 0.f;
#pragma unroll
  for (int nf = 0; nf < 4; ++nf) {
    union { unsigned short h[4]; uint2 u; } pk;
#pragma unroll
    for (int r = 0; r < 4; ++r) {
      float p = fexp2(s[nf][r] - mrow);
      pk.h[r] = f2bf(p);
      rs += p;
    }
    *reinterpret_cast<uint2*>(
        &pw[fr * 64 + (((2 * nf + (fg >> 1)) ^ (fr & 7)) * 8) + (fg & 1) * 4]) = pk.u;
  }
  lpart += rs;
  bf16x8 pf[2];
#pragma unroll
  for (int ks = 0; ks < 2; ++ks)
    pf[ks] = *reinterpret_cast<const bf16x8*>(
        &pw[fr * 64 + (((ks * 4 + fg) ^ (fr & 7)) * 8)]);
#pragma unroll
  for (int df = 0; df < 4; ++df)
#pragma unroll
    for (int ks = 0; ks < 2; ++ks)
      accO[df] = mfma16(pf[ks], vf[ks][df], accO[df]);
}

__global__ __launch_bounds__(256) void k_attn(
    const unsigned short* __restrict__ Qb, const unsigned short* __restrict__ Kb,
    const unsigned short* __restrict__ Vt, unsigned short* __restrict__ Ob) {
  __shared__ __align__(16) unsigned short Ks0[64 * 64], Ks1[64 * 64];
  __shared__ __align__(16) unsigned short Vs0[64 * 64], Vs1[64 * 64];
  __shared__ __align__(16) unsigned short p_lds[4][16 * 64];  // wave-private
  const int tid = threadIdx.x, lane = tid & 63, w = tid >> 6;
  const int fr = lane & 15, fg = lane >> 4;
  // bijective XCD swizzle: each XCD gets 128 consecutive ids = 4 heads (2MB L2)
  const int bid = (int)(blockIdx.x & 7) * 128 + (int)(blockIdx.x >> 3);
  const int qt = bid & 31, bh = bid >> 5;
  const unsigned short* Qp = Qb + ((size_t)bh * 2048 + qt * 64 + w * 16) * 64;
  const unsigned short* Kp = Kb + (size_t)bh * 2048 * 64;
  const unsigned short* Vp = Vt + (size_t)bh * 64 * 2048;
  unsigned short* pw = &p_lds[w][0];

  const int crow0 = w * 16 + (lane >> 3);  // staging row; j=1 adds 8
  bf16x8 qf[2];
#pragma unroll
  for (int ks = 0; ks < 2; ++ks)
    qf[ks] = *reinterpret_cast<const bf16x8*>(Qp + fr * 64 + ks * 32 + fg * 8);

  f32x4 accO[4] = {};
  float mrow = -1e30f, lpart = 0.f;

#define STAGE(KDST, VDST, kti)                                                \
  {                                                                           \
    const unsigned short* Kt_ = Kp + (kti) * 64 * 64;                         \
    _Pragma("unroll")                                                         \
    for (int j = 0; j < 2; ++j) {                                             \
      int cr = crow0 + j * 8;                                                 \
      int cs = (lane & 7) ^ (cr & 7);                                         \
      gld16(Kt_ + cr * 64 + cs * 8, (KDST) + (w * 2 + j) * 512);              \
      gld16(Vp + (size_t)cr * 2048 + (kti) * 64 + cs * 8,                     \
            (VDST) + (w * 2 + j) * 512);                                      \
    }                                                                         \
  }

  STAGE(Ks0, Vs0, 0);
  STAGE(Ks1, Vs1, 1);
  __syncthreads();
  for (int i = 0; i < 16; ++i) {
    attn_tile(Ks0, Vs0, pw, qf, fr, fg, accO, mrow, lpart);
    __syncthreads();
    if (i < 15) STAGE(Ks0, Vs0, 2 * i + 2);
    attn_tile(Ks1, Vs1, pw, qf, fr, fg, accO, mrow, lpart);
    __syncthreads();
    if (i < 15) STAGE(Ks1, Vs1, 2 * i + 3);
  }
#undef STAGE
  // epilogue: O[q][d], q = fg*4+r, d = df*16+fr; l lives at lane q=fr
  float lrow = lpart;
  lrow += __shfl_xor(lrow, 16);
  lrow += __shfl_xor(lrow, 32);
  float linv = 1.f / lrow;
  float lq[4];
#pragma unroll
  for (int r = 0; r < 4; ++r) lq[r] = __shfl(linv, fg * 4 + r);
  const int b_ = bh >> 4, h = bh & 15;
#pragma unroll
  for (int df = 0; df < 4; ++df)
#pragma unroll
    for (int r = 0; r < 4; ++r) {
      int nn = qt * 64 + w * 16 + fg * 4 + r;
      int d = df * 16 + fr;
      Ob[(size_t)(b_ * 2048 + nn) * 1024 + h * 64 + d] = f2bf(accO[df][r] * lq[r]);
    }
}

// ---------------- Proj GEMM: out[4096][1024] = Ob @ pwb^T + bias (fp32 out) -
__global__ __launch_bounds__(256) void k_proj(
    const unsigned short* __restrict__ A, const unsigned short* __restrict__ W,
    const float* __restrict__ bias, float* __restrict__ out) {
  const int K = 1024;
  __shared__ __align__(16) unsigned short As[128 * 32], Bs[128 * 32];
  const int tid = threadIdx.x, lane = tid & 63, wid = tid >> 6;
  const int wm = wid >> 1, wn = wid & 1, fr = lane & 15, fg = lane >> 4;
  const size_t bm = blockIdx.x, bn = blockIdx.y;
  const unsigned short* gA = A + bm * 128 * K;
  const unsigned short* gW = W + bn * 128 * K;
  f32x4 acc[4][4] = {};
  for (int k0 = 0; k0 < K; k0 += 32) {
#pragma unroll
    for (int c = 0; c < 2; ++c) {
      int bi = c * 4096 + wid * 1024 + lane * 16;
      int row = bi >> 6, ce = (bi & 63) >> 1;
      gld16(gA + (size_t)row * K + k0 + ce, As + c * 2048 + wid * 512);
      gld16(gW + (size_t)row * K + k0 + ce, Bs + c * 2048 + wid * 512);
    }
    __syncthreads();
    bf16x8 af[4], bw[4];
#pragma unroll
    for (int m = 0; m < 4; ++m)
      af[m] = *reinterpret_cast<const bf16x8*>(As + (wm * 64 + m * 16 + fr) * 32 + fg * 8);
#pragma unroll
    for (int n = 0; n < 4; ++n)
      bw[n] = *reinterpret_cast<const bf16x8*>(Bs + (wn * 64 + n * 16 + fr) * 32 + fg * 8);
#pragma unroll
    for (int m = 0; m < 4; ++m)
#pragma unroll
      for (int n = 0; n < 4; ++n)
        acc[m][n] = mfma16(af[m], bw[n], acc[m][n]);
    __syncthreads();
  }
  float bv[4];
#pragma unroll
  for (int n = 0; n < 4; ++n) bv[n] = bias[bn * 128 + wn * 64 + n * 16 + fr];
#pragma unroll
  for (int m = 0; m < 4; ++m)
#pragma unroll
    for (int n = 0; n < 4; ++n)
#pragma unroll
      for (int r = 0; r < 4; ++r) {
        size_t token = bm * 128 + wm * 64 + m * 16 + fg * 4 + r;
        int f = (int)bn * 128 + wn * 64 + n * 16 + fr;
        out[token * 1024 + f] = acc[m][n][r] + bv[n];
      }
}

extern "C" void kernel_launch(void* const* d_in, const int* in_sizes, int n_in,
                              void* d_out, int out_size, void* d_ws, size_t ws_size,
                              hipStream_t stream) {
  const float* x      = (const float*)d_in[0];
  const float* qkv_w  = (const float*)d_in[1];
  const float* qkv_b  = (const float*)d_in[2];
  const float* proj_w = (const float*)d_in[3];
  const float* proj_b = (const float*)d_in[4];
  float* out = (float*)d_out;
  char* ws = (char*)d_ws;
  unsigned short* xb  = (unsigned short*)(ws);
  unsigned short* wqb = (unsigned short*)(ws + (size_t)(8u << 20));
  unsigned short* pwb = (unsigned short*)(ws + (size_t)(14u << 20));
  unsigned short* Qb  = (unsigned short*)(ws + (size_t)(16u << 20));
  unsigned short* Kb  = (unsigned short*)(ws + (size_t)(24u << 20));
  unsigned short* Vt  = (unsigned short*)(ws + (size_t)(32u << 20));
  unsigned short* Ob  = (unsigned short*)(ws + (size_t)(40u << 20));

  k_conv<<<8192, 256, 0, stream>>>(x, qkv_w, proj_w, xb, wqb, pwb);
  k_qkv<<<dim3(32, 24), 256, 0, stream>>>(xb, wqb, qkv_b, Qb, Kb, Vt);
  k_attn<<<1024, 256, 0, stream>>>(Qb, Kb, Vt, Ob);
  k_proj<<<dim3(32, 8), 256, 0, stream>>>(Ob, pwb, proj_b, out);
}